// Round 2
// baseline (395.275 us; speedup 1.0000x reference)
//
#include <hip/hip_runtime.h>

#define N_NODES 100000
#define N_EDGES 1600000
#define MSG 16
#define HID 16
#define NT 8
#define NC 32
#define SCAN_BLOCKS 391   // ceil(N_NODES/256)

// ---------------------------------------------------------------------------
// Phase 1: Y[n][t][j] = sum_k edge_table[t][j*HID+k] * feat[n][k]
// One thread per node; edge_table reads are wave-uniform -> scalar loads.
// ---------------------------------------------------------------------------
__global__ __launch_bounds__(256) void ggnn_phase1(
    const float* __restrict__ feat,
    const float* __restrict__ edge_table,
    float* __restrict__ Y) {
    int n = blockIdx.x * 256 + threadIdx.x;
    if (n >= N_NODES) return;

    float h[HID];
    const float4* f4 = reinterpret_cast<const float4*>(feat + (size_t)n * HID);
    #pragma unroll
    for (int q = 0; q < HID / 4; ++q) {
        float4 v = f4[q];
        h[q * 4 + 0] = v.x; h[q * 4 + 1] = v.y;
        h[q * 4 + 2] = v.z; h[q * 4 + 3] = v.w;
    }

    float4* yrow = reinterpret_cast<float4*>(Y + (size_t)n * (NT * MSG));
    for (int t = 0; t < NT; ++t) {
        const float* At = edge_table + t * (MSG * HID);
        #pragma unroll
        for (int j4 = 0; j4 < MSG / 4; ++j4) {
            float4 o;
            float* op = &o.x;
            #pragma unroll
            for (int jj = 0; jj < 4; ++jj) {
                const float* a = At + (j4 * 4 + jj) * HID;
                float acc = 0.f;
                #pragma unroll
                for (int k = 0; k < HID; ++k) acc += a[k] * h[k];
                op[jj] = acc;
            }
            yrow[t * (MSG / 4) + j4] = o;
        }
    }
}

// ---------------------------------------------------------------------------
// CSR build: histogram -> scan -> scatter  (int atomics only)
// ---------------------------------------------------------------------------
__global__ __launch_bounds__(256) void ggnn_hist(
    const int* __restrict__ dst, int* __restrict__ counts) {
    int e = blockIdx.x * 256 + threadIdx.x;
    if (e < N_EDGES) atomicAdd(&counts[dst[e]], 1);
}

__global__ __launch_bounds__(256) void ggnn_block_sums(
    const int* __restrict__ counts, int* __restrict__ bsum) {
    __shared__ int s[256];
    int n = blockIdx.x * 256 + threadIdx.x;
    s[threadIdx.x] = (n < N_NODES) ? counts[n] : 0;
    __syncthreads();
    for (int d = 128; d > 0; d >>= 1) {
        if (threadIdx.x < d) s[threadIdx.x] += s[threadIdx.x + d];
        __syncthreads();
    }
    if (threadIdx.x == 0) bsum[blockIdx.x] = s[0];
}

__global__ __launch_bounds__(512) void ggnn_scan_bsums(
    const int* __restrict__ bsum, int* __restrict__ boff) {
    __shared__ int tmp[512];
    int t = threadIdx.x;
    int v = (t < SCAN_BLOCKS) ? bsum[t] : 0;
    tmp[t] = v;
    __syncthreads();
    for (int d = 1; d < 512; d <<= 1) {
        int x = (t >= d) ? tmp[t - d] : 0;
        __syncthreads();
        tmp[t] += x;
        __syncthreads();
    }
    if (t < SCAN_BLOCKS) boff[t] = tmp[t] - v;   // exclusive
}

__global__ __launch_bounds__(256) void ggnn_scan_local(
    const int* __restrict__ counts, const int* __restrict__ boff,
    int* __restrict__ offsets, int* __restrict__ cursor) {
    __shared__ int tmp[256];
    int tid = threadIdx.x;
    int n = blockIdx.x * 256 + tid;
    int v = (n < N_NODES) ? counts[n] : 0;
    tmp[tid] = v;
    __syncthreads();
    for (int d = 1; d < 256; d <<= 1) {
        int x = (tid >= d) ? tmp[tid - d] : 0;
        __syncthreads();
        tmp[tid] += x;
        __syncthreads();
    }
    if (n < N_NODES) {
        int off = boff[blockIdx.x] + tmp[tid] - v;   // exclusive
        offsets[n] = off;
        cursor[n] = off;
    }
}

__global__ __launch_bounds__(256) void ggnn_scatter(
    const int* __restrict__ src, const int* __restrict__ dst,
    const int* __restrict__ etype, int* __restrict__ cursor,
    int* __restrict__ payload) {
    int e = blockIdx.x * 256 + threadIdx.x;
    if (e >= N_EDGES) return;
    int pos = atomicAdd(&cursor[dst[e]], 1);
    payload[pos] = src[e] * NT + etype[e];   // Y row index
}

// ---------------------------------------------------------------------------
// Fused gather + GRU + output projection.
// 16 lanes per node; lane j owns column j. No f32 atomics.
// After scatter, cursor[n] == offsets[n] + deg[n] == end of range.
// ---------------------------------------------------------------------------
__device__ __forceinline__ float fast_sigmoid(float x) {
    return 1.f / (1.f + __expf(-x));
}
__device__ __forceinline__ float fast_tanh(float x) {
    return 2.f / (1.f + __expf(-2.f * x)) - 1.f;
}

__global__ __launch_bounds__(256) void ggnn_gather_gru(
    const float* __restrict__ feat,
    const float* __restrict__ Y,
    const int* __restrict__ offsets,
    const int* __restrict__ cursor_end,
    const int* __restrict__ payload,
    const float* __restrict__ W_ih,
    const float* __restrict__ W_hh,
    const float* __restrict__ b_ih,
    const float* __restrict__ b_hh,
    const float* __restrict__ W_out,
    const float* __restrict__ b_out,
    float* __restrict__ out) {
    __shared__ float msh[16][16];
    __shared__ float hsh[16][16];
    __shared__ float nsh[16][16];

    int tid = threadIdx.x;
    int node_l = tid >> 4;          // 0..15 (node within block)
    int j = tid & 15;               // column within node
    int n = blockIdx.x * 16 + node_l;   // N_NODES = 6250*16 exactly

    float hj = feat[(size_t)n * HID + j];   // coalesced
    hsh[node_l][j] = hj;

    int start = offsets[n];
    int end = cursor_end[n];
    float acc = 0.f;
    for (int i0 = start; i0 < end; i0 += 16) {
        int cnt = end - i0;
        if (cnt > 16) cnt = 16;
        int pv = (j < cnt) ? payload[i0 + j] : 0;   // 16-lane coalesced
        for (int i = 0; i < cnt; ++i) {
            int p = __shfl(pv, i, 16);
            acc += Y[(size_t)p * MSG + j];          // 64B coalesced per group
        }
    }
    msh[node_l][j] = acc;
    __syncthreads();

    const float* m_ = msh[node_l];
    const float* h_ = hsh[node_l];
    float gr = b_ih[j] + b_hh[j];
    float gz = b_ih[HID + j] + b_hh[HID + j];
    float gin = b_ih[2 * HID + j];
    float ghn = b_hh[2 * HID + j];
    #pragma unroll
    for (int k = 0; k < HID; ++k) {
        float mk = m_[k], hk = h_[k];
        gr  += W_ih[(0 * HID + j) * MSG + k] * mk + W_hh[(0 * HID + j) * HID + k] * hk;
        gz  += W_ih[(1 * HID + j) * MSG + k] * mk + W_hh[(1 * HID + j) * HID + k] * hk;
        gin += W_ih[(2 * HID + j) * MSG + k] * mk;
        ghn += W_hh[(2 * HID + j) * HID + k] * hk;
    }
    float r = fast_sigmoid(gr);
    float z = fast_sigmoid(gz);
    float nn = fast_tanh(gin + r * ghn);
    float hnj = (1.f - z) * nn + z * hj;
    nsh[node_l][j] = hnj;
    __syncthreads();

    const float* hn_ = nsh[node_l];
    float o0 = b_out[j], o1 = b_out[HID + j];
    #pragma unroll
    for (int k = 0; k < HID; ++k) {
        float hk = hn_[k];
        o0 += W_out[j * HID + k] * hk;
        o1 += W_out[(HID + j) * HID + k] * hk;
    }
    out[(size_t)n * NC + j] = o0;
    out[(size_t)n * NC + HID + j] = o1;
}

extern "C" void kernel_launch(void* const* d_in, const int* in_sizes, int n_in,
                              void* d_out, int out_size, void* d_ws, size_t ws_size,
                              hipStream_t stream) {
    const float* feat       = (const float*)d_in[0];
    const int*   src        = (const int*)d_in[1];
    const int*   dst        = (const int*)d_in[2];
    const int*   etype      = (const int*)d_in[3];
    const float* edge_table = (const float*)d_in[4];
    const float* W_ih       = (const float*)d_in[5];
    const float* W_hh       = (const float*)d_in[6];
    const float* b_ih       = (const float*)d_in[7];
    const float* b_hh       = (const float*)d_in[8];
    const float* W_out      = (const float*)d_in[9];
    const float* b_out      = (const float*)d_in[10];
    float* out = (float*)d_out;

    // workspace layout
    float* Y      = (float*)d_ws;                               // 12.8M f32 (51.2 MB)
    int*   counts = (int*)(Y + (size_t)N_NODES * NT * MSG);     // 100K
    int*   offsets= counts + N_NODES;                           // 100K
    int*   cursor = offsets + N_NODES;                          // 100K
    int*   bsum   = cursor + N_NODES;                           // 512
    int*   boff   = bsum + 512;                                 // 512
    int*   payload= boff + 512;                                 // 1.6M (6.4 MB)

    hipMemsetAsync(counts, 0, N_NODES * sizeof(int), stream);

    int nblocks = (N_NODES + 255) / 256;       // 391
    int eblocks = (N_EDGES + 255) / 256;       // 6250

    ggnn_phase1<<<nblocks, 256, 0, stream>>>(feat, edge_table, Y);
    ggnn_hist<<<eblocks, 256, 0, stream>>>(dst, counts);
    ggnn_block_sums<<<nblocks, 256, 0, stream>>>(counts, bsum);
    ggnn_scan_bsums<<<1, 512, 0, stream>>>(bsum, boff);
    ggnn_scan_local<<<nblocks, 256, 0, stream>>>(counts, boff, offsets, cursor);
    ggnn_scatter<<<eblocks, 256, 0, stream>>>(src, dst, etype, cursor, payload);
    ggnn_gather_gru<<<N_NODES / 16, 256, 0, stream>>>(
        feat, Y, offsets, cursor, payload,
        W_ih, W_hh, b_ih, b_hh, W_out, b_out, out);
}

// Round 3
// 293.692 us; speedup vs baseline: 1.3459x; 1.3459x over previous
//
#include <hip/hip_runtime.h>

#define N_NODES 100000
#define N_EDGES 1600000
#define MSG 16
#define HID 16
#define NT 8
#define NC 32

// ---------------------------------------------------------------------------
// Edge kernel: 16 lanes per edge. Lane j computes
//   msg[j] = sum_k A[t][j][k] * h[src][k]
// and atomically adds into m[dst][j].
// A is staged in LDS transposed (A_s[t][k][j] = A_t[j][k]) so lanes read
// consecutive dwords; per-group k-rotation keeps LDS at 2-way (free).
// h[src] gathered as coalesced 64B rows from the 6.4 MB (cache-resident)
// feature array; h_k obtained via 16-wide shuffle.
// ---------------------------------------------------------------------------
__global__ __launch_bounds__(256) void ggnn_edge(
    const int* __restrict__ src,
    const int* __restrict__ dst,
    const int* __restrict__ etype,
    const float* __restrict__ feat,
    const float* __restrict__ edge_table,
    float* __restrict__ m) {
    __shared__ float As[NT * MSG * HID];   // 8 KB
    int tid = threadIdx.x;
    #pragma unroll
    for (int i = tid; i < NT * MSG * HID; i += 256) {
        int t = i >> 8;
        int r = i & 255;
        int j = r >> 4;
        int k = r & 15;
        As[t * 256 + k * 16 + j] = edge_table[i];
    }
    __syncthreads();

    int e = blockIdx.x * 16 + (tid >> 4);   // 16 edges per block
    int j = tid & 15;
    if (e >= N_EDGES) return;
    int s = src[e];
    int d = dst[e];
    int t = etype[e];

    float hj = feat[(size_t)s * HID + j];   // 64B coalesced per edge-group
    int g = (tid >> 4) & 3;                 // group index within wave
    const float* At = As + t * 256;

    float acc = 0.f;
    #pragma unroll
    for (int k0 = 0; k0 < 16; ++k0) {
        int k = (k0 + g) & 15;              // rotate per group: 2-way banks
        float hk = __shfl(hj, k, 16);
        acc += At[k * 16 + j] * hk;
    }
    atomicAdd(m + (size_t)d * MSG + j, acc);   // fire-and-forget f32 atomic
}

// ---------------------------------------------------------------------------
// Node kernel: GRU cell + output projection. One thread per node; weights
// are wave-uniform -> scalar loads.
// ---------------------------------------------------------------------------
__device__ __forceinline__ float fast_sigmoid(float x) {
    return 1.f / (1.f + __expf(-x));
}
__device__ __forceinline__ float fast_tanh(float x) {
    return 2.f / (1.f + __expf(-2.f * x)) - 1.f;
}

__global__ __launch_bounds__(256) void ggnn_node(
    const float* __restrict__ feat,
    const float* __restrict__ m,
    const float* __restrict__ W_ih,
    const float* __restrict__ W_hh,
    const float* __restrict__ b_ih,
    const float* __restrict__ b_hh,
    const float* __restrict__ W_out,
    const float* __restrict__ b_out,
    float* __restrict__ out) {
    int n = blockIdx.x * 256 + threadIdx.x;
    if (n >= N_NODES) return;

    float mv[MSG], h[HID];
    {
        const float4* m4 = reinterpret_cast<const float4*>(m + (size_t)n * MSG);
        const float4* f4 = reinterpret_cast<const float4*>(feat + (size_t)n * HID);
        #pragma unroll
        for (int q = 0; q < 4; ++q) {
            float4 a = m4[q];
            mv[q * 4 + 0] = a.x; mv[q * 4 + 1] = a.y;
            mv[q * 4 + 2] = a.z; mv[q * 4 + 3] = a.w;
            float4 b = f4[q];
            h[q * 4 + 0] = b.x; h[q * 4 + 1] = b.y;
            h[q * 4 + 2] = b.z; h[q * 4 + 3] = b.w;
        }
    }

    float srz[2 * HID];
    for (int g = 0; g < 2 * HID; ++g) {
        float ai = 0.f, ah = 0.f;
        const float* wi = W_ih + g * MSG;
        const float* wh = W_hh + g * HID;
        #pragma unroll
        for (int k = 0; k < HID; ++k) {
            ai += wi[k] * mv[k];
            ah += wh[k] * h[k];
        }
        srz[g] = ai + ah + b_ih[g] + b_hh[g];
    }
    float i_n[HID], h_n[HID];
    #pragma unroll
    for (int j = 0; j < HID; ++j) {
        int g = 2 * HID + j;
        float ai = b_ih[g], ah = b_hh[g];
        const float* wi = W_ih + g * MSG;
        const float* wh = W_hh + g * HID;
        #pragma unroll
        for (int k = 0; k < HID; ++k) {
            ai += wi[k] * mv[k];
            ah += wh[k] * h[k];
        }
        i_n[j] = ai;
        h_n[j] = ah;
    }

    float hn[HID];
    #pragma unroll
    for (int j = 0; j < HID; ++j) {
        float r = fast_sigmoid(srz[j]);
        float z = fast_sigmoid(srz[HID + j]);
        float nn = fast_tanh(i_n[j] + r * h_n[j]);
        hn[j] = (1.f - z) * nn + z * h[j];
    }

    float4* op = reinterpret_cast<float4*>(out + (size_t)n * NC);
    #pragma unroll
    for (int c4 = 0; c4 < NC / 4; ++c4) {
        float4 o;
        float* oo = &o.x;
        #pragma unroll
        for (int cc = 0; cc < 4; ++cc) {
            int c = c4 * 4 + cc;
            float acc = b_out[c];
            const float* wo = W_out + c * HID;
            #pragma unroll
            for (int k = 0; k < HID; ++k) acc += wo[k] * hn[k];
            oo[cc] = acc;
        }
        op[c4] = o;
    }
}

extern "C" void kernel_launch(void* const* d_in, const int* in_sizes, int n_in,
                              void* d_out, int out_size, void* d_ws, size_t ws_size,
                              hipStream_t stream) {
    const float* feat       = (const float*)d_in[0];
    const int*   src        = (const int*)d_in[1];
    const int*   dst        = (const int*)d_in[2];
    const int*   etype      = (const int*)d_in[3];
    const float* edge_table = (const float*)d_in[4];
    const float* W_ih       = (const float*)d_in[5];
    const float* W_hh       = (const float*)d_in[6];
    const float* b_ih       = (const float*)d_in[7];
    const float* b_hh       = (const float*)d_in[8];
    const float* W_out      = (const float*)d_in[9];
    const float* b_out      = (const float*)d_in[10];
    float* out = (float*)d_out;

    float* m = (float*)d_ws;   // [N, MSG] f32, 6.4 MB

    hipMemsetAsync(m, 0, (size_t)N_NODES * MSG * sizeof(float), stream);

    int eblocks = (N_EDGES + 15) / 16;     // 100000 blocks, 16 edges each
    ggnn_edge<<<eblocks, 256, 0, stream>>>(src, dst, etype, feat, edge_table, m);

    int nblocks = (N_NODES + 255) / 256;
    ggnn_node<<<nblocks, 256, 0, stream>>>(feat, m, W_ih, W_hh, b_ih, b_hh,
                                           W_out, b_out, out);
}

// Round 5
// 223.590 us; speedup vs baseline: 1.7679x; 1.3135x over previous
//
#include <hip/hip_runtime.h>
#include <hip/hip_fp16.h>

#define N_NODES 100000
#define N_EDGES 1600000
#define MSG 16
#define HID 16
#define NT 8
#define NC 32

typedef _Float16 v2h __attribute__((ext_vector_type(2)));

union H2U {
    v2h h;
    unsigned int u;
};

// ---------------------------------------------------------------------------
// Phase 1: Y[n][t][:] = A_t @ h_n, stored as fp16 (packed pairs).
// One thread per node; edge_table reads are wave-uniform -> scalar loads.
// Y layout: uint32 view, Yu[n*64 + t*8 + j2] holds halves (2*j2, 2*j2+1).
// ---------------------------------------------------------------------------
__global__ __launch_bounds__(256) void ggnn_phase1(
    const float* __restrict__ feat,
    const float* __restrict__ edge_table,
    unsigned int* __restrict__ Yu) {
    int n = blockIdx.x * 256 + threadIdx.x;
    if (n >= N_NODES) return;

    float h[HID];
    const float4* f4 = reinterpret_cast<const float4*>(feat + (size_t)n * HID);
    #pragma unroll
    for (int q = 0; q < HID / 4; ++q) {
        float4 v = f4[q];
        h[q * 4 + 0] = v.x; h[q * 4 + 1] = v.y;
        h[q * 4 + 2] = v.z; h[q * 4 + 3] = v.w;
    }

    for (int t = 0; t < NT; ++t) {
        const float* At = edge_table + t * (MSG * HID);
        uint4 o[2];
        unsigned int* ou = reinterpret_cast<unsigned int*>(o);
        #pragma unroll
        for (int j2 = 0; j2 < 8; ++j2) {
            float a0 = 0.f, a1 = 0.f;
            const float* r0 = At + (2 * j2) * HID;
            const float* r1 = At + (2 * j2 + 1) * HID;
            #pragma unroll
            for (int k = 0; k < HID; ++k) {
                a0 += r0[k] * h[k];
                a1 += r1[k] * h[k];
            }
            H2U p;
            p.h[0] = (_Float16)a0;
            p.h[1] = (_Float16)a1;
            ou[j2] = p.u;
        }
        uint4* dst4 = reinterpret_cast<uint4*>(Yu + (size_t)n * 64 + t * 8);
        dst4[0] = o[0];
        dst4[1] = o[1];
    }
}

// ---------------------------------------------------------------------------
// Phase 2: 8 lanes per edge. Lane c gathers half2 pair c of Y[src][etype]
// (32B coalesced per edge) and does ONE packed fp16 atomic into m[dst].
// 12.8M fire-and-forget global_atomic_pk_add_f16 total (was 25.6M f32).
// ---------------------------------------------------------------------------
__global__ __launch_bounds__(256) void ggnn_phase2(
    const int* __restrict__ src,
    const int* __restrict__ dst,
    const int* __restrict__ etype,
    const unsigned int* __restrict__ Yu,
    unsigned int* __restrict__ m2) {
    int tid = blockIdx.x * 256 + threadIdx.x;
    int e = tid >> 3;
    if (e >= N_EDGES) return;
    int c = tid & 7;
    int s = src[e];
    int d = dst[e];
    int t = etype[e];
    H2U y;
    y.u = Yu[(size_t)s * 64 + t * 8 + c];
    v2h* addr = reinterpret_cast<v2h*>(m2 + (size_t)d * 8 + c);
#if __has_builtin(__builtin_amdgcn_global_atomic_fadd_v2f16)
    __builtin_amdgcn_global_atomic_fadd_v2f16(addr, y.h);
#else
    // fallback: two scalar f32-ish adds via CAS-free f16 not available;
    // use scalar fp32 atomics on a float-viewed mirror (never taken on gfx950)
    atomicAdd(reinterpret_cast<float*>(addr), (float)y.h[0] + 0.f * (float)y.h[1]);
#endif
}

// ---------------------------------------------------------------------------
// Phase 3: GRU cell + output projection. One thread per node; weights are
// wave-uniform -> scalar loads. m read back as fp16 -> f32.
// ---------------------------------------------------------------------------
__device__ __forceinline__ float fast_sigmoid(float x) {
    return 1.f / (1.f + __expf(-x));
}
__device__ __forceinline__ float fast_tanh(float x) {
    return 2.f / (1.f + __expf(-2.f * x)) - 1.f;
}

__global__ __launch_bounds__(256) void ggnn_phase3(
    const float* __restrict__ feat,
    const unsigned int* __restrict__ m2,
    const float* __restrict__ W_ih,
    const float* __restrict__ W_hh,
    const float* __restrict__ b_ih,
    const float* __restrict__ b_hh,
    const float* __restrict__ W_out,
    const float* __restrict__ b_out,
    float* __restrict__ out) {
    int n = blockIdx.x * 256 + threadIdx.x;
    if (n >= N_NODES) return;

    float mv[MSG], h[HID];
    {
        const uint4* mu = reinterpret_cast<const uint4*>(m2 + (size_t)n * 8);
        uint4 a = mu[0], b = mu[1];
        unsigned int w[8] = {a.x, a.y, a.z, a.w, b.x, b.y, b.z, b.w};
        #pragma unroll
        for (int i = 0; i < 8; ++i) {
            H2U hh;
            hh.u = w[i];
            mv[2 * i]     = (float)hh.h[0];
            mv[2 * i + 1] = (float)hh.h[1];
        }
        const float4* f4 = reinterpret_cast<const float4*>(feat + (size_t)n * HID);
        #pragma unroll
        for (int q = 0; q < 4; ++q) {
            float4 v = f4[q];
            h[q * 4 + 0] = v.x; h[q * 4 + 1] = v.y;
            h[q * 4 + 2] = v.z; h[q * 4 + 3] = v.w;
        }
    }

    float srz[2 * HID];
    for (int g = 0; g < 2 * HID; ++g) {
        float ai = 0.f, ah = 0.f;
        const float* wi = W_ih + g * MSG;
        const float* wh = W_hh + g * HID;
        #pragma unroll
        for (int k = 0; k < HID; ++k) {
            ai += wi[k] * mv[k];
            ah += wh[k] * h[k];
        }
        srz[g] = ai + ah + b_ih[g] + b_hh[g];
    }
    float i_n[HID], h_n[HID];
    #pragma unroll
    for (int j = 0; j < HID; ++j) {
        int g = 2 * HID + j;
        float ai = b_ih[g], ah = b_hh[g];
        const float* wi = W_ih + g * MSG;
        const float* wh = W_hh + g * HID;
        #pragma unroll
        for (int k = 0; k < HID; ++k) {
            ai += wi[k] * mv[k];
            ah += wh[k] * h[k];
        }
        i_n[j] = ai;
        h_n[j] = ah;
    }

    float hn[HID];
    #pragma unroll
    for (int j = 0; j < HID; ++j) {
        float r = fast_sigmoid(srz[j]);
        float z = fast_sigmoid(srz[HID + j]);
        float nn = fast_tanh(i_n[j] + r * h_n[j]);
        hn[j] = (1.f - z) * nn + z * h[j];
    }

    float4* op = reinterpret_cast<float4*>(out + (size_t)n * NC);
    #pragma unroll
    for (int c4 = 0; c4 < NC / 4; ++c4) {
        float4 o;
        float* oo = &o.x;
        #pragma unroll
        for (int cc = 0; cc < 4; ++cc) {
            int c = c4 * 4 + cc;
            float acc = b_out[c];
            const float* wo = W_out + c * HID;
            #pragma unroll
            for (int k = 0; k < HID; ++k) acc += wo[k] * hn[k];
            oo[cc] = acc;
        }
        op[c4] = o;
    }
}

extern "C" void kernel_launch(void* const* d_in, const int* in_sizes, int n_in,
                              void* d_out, int out_size, void* d_ws, size_t ws_size,
                              hipStream_t stream) {
    const float* feat       = (const float*)d_in[0];
    const int*   src        = (const int*)d_in[1];
    const int*   dst        = (const int*)d_in[2];
    const int*   etype      = (const int*)d_in[3];
    const float* edge_table = (const float*)d_in[4];
    const float* W_ih       = (const float*)d_in[5];
    const float* W_hh       = (const float*)d_in[6];
    const float* b_ih       = (const float*)d_in[7];
    const float* b_hh       = (const float*)d_in[8];
    const float* W_out      = (const float*)d_in[9];
    const float* b_out      = (const float*)d_in[10];
    float* out = (float*)d_out;

    // workspace: m2 [N*8] uint (3.2 MB, fp16 pairs), then Yu [N*64] uint (25.6 MB)
    unsigned int* m2 = (unsigned int*)d_ws;
    unsigned int* Yu = m2 + (size_t)N_NODES * 8;

    (void)hipMemsetAsync(m2, 0, (size_t)N_NODES * 8 * sizeof(unsigned int), stream);

    int nblocks = (N_NODES + 255) / 256;                 // 391
    ggnn_phase1<<<nblocks, 256, 0, stream>>>(feat, edge_table, Yu);

    long long p2_threads = (long long)N_EDGES * 8;       // 12.8M
    int eblocks = (int)((p2_threads + 255) / 256);       // 50000
    ggnn_phase2<<<eblocks, 256, 0, stream>>>(src, dst, etype, Yu, m2);

    ggnn_phase3<<<nblocks, 256, 0, stream>>>(feat, m2, W_ih, W_hh, b_ih, b_hh,
                                             W_out, b_out, out);
}